// Round 12
// baseline (35.504 us; speedup 1.0000x reference)
//
#include <hip/hip_runtime.h>
#include <math.h>

#define N_GAUSS 2048
#define IMG_H 256
#define IMG_W 256
#define NPIX (IMG_H * IMG_W)
#define EPS 1e-4f

#define TILE 8
#define TILES_X (IMG_W / TILE)             // 32
#define NTILES (TILES_X * (IMG_H / TILE))  // 1024
#define NW 8                               // waves per block
#define SEG (N_GAUSS / NW)                 // 256 gaussians per wave-segment
#define CAP 64                             // LDS-staged candidates per segment
// Half-diagonal of the 8x8 pixel-center extent: 3.5*sqrt(2)/256 = 0.01933495
#define D_HALF 0.019336f                   // strictly above the exact value

// Strict-< sorted-insert ladder; lowest index wins ties (top_k stable order).
#define LADDER(T, G)                                                     \
    if ((T) < v7) {                                                      \
        const bool c0 = (T) < v0, c1 = (T) < v1, c2 = (T) < v2;          \
        const bool c3 = (T) < v3, c4 = (T) < v4, c5 = (T) < v5;          \
        const bool c6 = (T) < v6;                                        \
        v7 = c6 ? v6 : (T);            i7 = c6 ? i6 : (G);               \
        v6 = c6 ? (c5 ? v5 : (T)) : v6; i6 = c6 ? (c5 ? i5 : (G)) : i6;  \
        v5 = c5 ? (c4 ? v4 : (T)) : v5; i5 = c5 ? (c4 ? i4 : (G)) : i5;  \
        v4 = c4 ? (c3 ? v3 : (T)) : v4; i4 = c4 ? (c3 ? i3 : (G)) : i4;  \
        v3 = c3 ? (c2 ? v2 : (T)) : v3; i3 = c3 ? (c2 ? i2 : (G)) : i3;  \
        v2 = c2 ? (c1 ? v1 : (T)) : v2; i2 = c2 ? (c1 ? i1 : (G)) : i2;  \
        v1 = c1 ? (c0 ? v0 : (T)) : v1; i1 = c1 ? (c0 ? i0 : (G)) : i1;  \
        v0 = c0 ? (T) : v0;            i0 = c0 ? (G) : i0;               \
    }

// Compare-exchange on constant-indexed array elems (registers after unroll).
#define CE(a, i, j)                                   \
    { float lo_ = fminf(a[i], a[j]);                  \
      float hi_ = fmaxf(a[i], a[j]);                  \
      a[i] = lo_; a[j] = hi_; }

// Sort first 4 elements ascending (5 comparators).
#define SORT4(a) CE(a,0,1) CE(a,2,3) CE(a,0,2) CE(a,1,3) CE(a,1,2)

// In-wave exact top-8 reduce (verbatim from passing R6-R11 kernels): each lane
// holds an ascending 8-list (INF-padded); afterwards every lane holds the
// wave's exact sorted top-8 (cur[7] is wave-uniform).
__device__ __forceinline__ void top8_butterfly(float (&cur)[8]) {
#pragma unroll
    for (int m = 1; m < 64; m <<= 1) {
        float oth[8];
#pragma unroll
        for (int k = 0; k < 8; ++k) oth[k] = __shfl_xor(cur[k], m, 64);
        float t_[8];
#pragma unroll
        for (int k = 0; k < 8; ++k) t_[k] = fminf(cur[k], oth[7 - k]);
        CE(t_,0,4) CE(t_,1,5) CE(t_,2,6) CE(t_,3,7)
        CE(t_,0,2) CE(t_,1,3) CE(t_,4,6) CE(t_,5,7)
        CE(t_,0,1) CE(t_,2,3) CE(t_,4,5) CE(t_,6,7)
#pragma unroll
        for (int k = 0; k < 8; ++k) cur[k] = t_[k];
    }
}

// Bit-exact reference arithmetic (one rounding per op, no fma).
#define PROC_EXACT(AX, AY, AC, AS, BX, BY, G)                            \
    {                                                                    \
        float dx = __fsub_rn(px, (AX));                                  \
        float dy = __fsub_rn(py, (AY));                                  \
        float lx = __fadd_rn(__fmul_rn(dx, (AC)), __fmul_rn(dy, (AS)));  \
        float ly = __fadd_rn(__fmul_rn(-dx, (AS)), __fmul_rn(dy, (AC))); \
        float aa = __fmul_rn(lx, (BX));                                  \
        float bb = __fmul_rn(ly, (BY));                                  \
        float t2 = __fadd_rn(__fmul_rn(aa, aa), __fmul_rn(bb, bb));      \
        LADDER(t2, (G))                                                  \
    }

// 8-wave wave-local pipeline, one barrier. Wave w owns segment [w*256, w*256+256):
//  A) fp32 screen of own segment (rlo, rp); B) wave-local exact 8th-smallest
//  cut (valid superset bound: V8_p(global) <= V8_p(segment) <= cut_w; Lipschitz
//  rlo <= r_p; 0.01 slack absorbs fp32/trig error — proof as R4-R11);
//  C) register-ballot ordered compaction + LDS staging; D) one masked f64
//  sincos batch (bit-identical trig) + LDS-broadcast exact ladder, ascending
//  index; E) barrier, wave 0 merges 8 ascending lists + blend.
__launch_bounds__(512, 8)
__global__ void fused_kernel(const float* __restrict__ xy,
                             const float* __restrict__ scale,
                             const float* __restrict__ rot,
                             const float* __restrict__ feat,
                             float* __restrict__ out) {
    __shared__ float4 qa[NW][CAP];            // 8 KB: staged x,y,sx,sy
    __shared__ float2 qt[NW][CAP];            // 4 KB: rot -> (cos,sin)
    __shared__ unsigned short qidx[NW][SEG];  // 4 KB: candidate ids (full seg)
    __shared__ float          lt[NW][8][64];  // 16 KB merge values
    __shared__ unsigned short li[NW][8][64];  // 8 KB merge indices
                                              // total 40960 B -> 4 blocks/CU

    const int tid  = threadIdx.x;
    const int lane = tid & 63;
    const int w    = tid >> 6;
    const int tile = blockIdx.x;

    // ---------------- Phase A: wave-local fp32 screen ----------------------
    const float cx = (float)((tile & (TILES_X - 1)) * TILE + 4) * (1.0f / IMG_W);
    const float cy = (float)((tile / TILES_X) * TILE + 4) * (1.0f / IMG_H);

    float rot_r[4], rlo_r[4], cur[8];
#pragma unroll
    for (int s = 0; s < 4; ++s) {
        int g = w * SEG + s * 64 + lane;
        float2 xyg = ((const float2*)xy)[g];
        float2 scg = ((const float2*)scale)[g];
        rot_r[s] = rot[g];
        float sn, cs2;
        __sincosf(rot_r[s], &sn, &cs2);
        float dx = cx - xyg.x;
        float dy = cy - xyg.y;
        float lx = dx * cs2 + dy * sn;
        float ly = dy * cs2 - dx * sn;
        float a  = lx * scg.x;
        float b  = ly * scg.y;
        float rr = sqrtf(a * a + b * b);
        float m  = fmaxf(scg.x, scg.y) * D_HALF;
        rlo_r[s] = rr - m;
        cur[s]   = rr + m;
    }
    cur[4] = INFINITY; cur[5] = INFINITY; cur[6] = INFINITY; cur[7] = INFINITY;
    SORT4(cur)

    // ---------------- Phase B: wave-local exact cut (no barrier) -----------
    top8_butterfly(cur);
    float cut = cur[7];
    cut = cut + 0.01f + 1e-4f * cut;     // slack >> all error budgets

    // ---------------- Phase C: register-ballot ordered compaction ----------
    unsigned base = 0;
#pragma unroll
    for (int s = 0; s < 4; ++s) {
        int g = w * SEG + s * 64 + lane;
        bool keep = rlo_r[s] <= cut;
        unsigned long long mask = __ballot(keep);
        if (keep) {
            unsigned pos = base + (unsigned)__popcll(mask & ((1ull << lane) - 1ull));
            qidx[w][pos] = (unsigned short)g;
            if (pos < CAP) {
                float2 xyg = ((const float2*)xy)[g];   // L1/L2 hit
                float2 scg = ((const float2*)scale)[g];
                qa[w][pos] = make_float4(xyg.x, xyg.y, scg.x, scg.y);
                qt[w][pos].x = rot_r[s];
            }
        }
        base += (unsigned)__popcll(mask);
    }
    const int cnt = (int)base;           // wave-uniform (ballot-derived)

    // ---------------- Phase D: bit-exact top-8 over own segment ------------
    const int jcap = cnt < CAP ? cnt : CAP;
    if (lane < jcap) {
        // Correctly-rounded fp32 trig via f64 sincos — bit-identical to the
        // (float)cos((double)r) path used since R2.
        double sd, cd;
        sincos((double)qt[w][lane].x, &sd, &cd);
        qt[w][lane] = make_float2((float)cd, (float)sd);
    }

    const int pxi = (tile & (TILES_X - 1)) * TILE + (lane & 7);
    const int pyi = (tile / TILES_X) * TILE + (lane >> 3);
    const int p   = pyi * IMG_W + pxi;
    const float px = (pxi + 0.5f) * (1.0f / IMG_W);
    const float py = (pyi + 0.5f) * (1.0f / IMG_H);

    float v0 = INFINITY, v1 = INFINITY, v2 = INFINITY, v3 = INFINITY;
    float v4 = INFINITY, v5 = INFINITY, v6 = INFINITY, v7 = INFINITY;
    int   i0 = 0, i1 = 0, i2 = 0, i3 = 0, i4 = 0, i5 = 0, i6 = 0, i7 = 0;

    for (int j = 0; j < jcap; ++j) {
        float4 a4 = qa[w][j];            // uniform addr -> LDS broadcast
        float2 ct = qt[w][j];
        int    g  = (int)qidx[w][j];
        PROC_EXACT(a4.x, a4.y, ct.x, ct.y, a4.z, a4.w, g)
    }
    // Overflow (cnt > CAP): rare/never for this input; R7-style shuffle
    // broadcast batches, values bit-identical (global reload + f64 trig).
    for (int b = CAP; b < cnt; b += 64) {
        int t = b + lane;
        int gg = (t < cnt) ? (int)qidx[w][t] : 0;
        float2 xyg = ((const float2*)xy)[gg];
        float2 scg = ((const float2*)scale)[gg];
        double sd, cd;
        sincos((double)rot[gg], &sd, &cd);
        float cc = (float)cd, ss = (float)sd;
        int lim = cnt - b; if (lim > 64) lim = 64;
        for (int j = 0; j < lim; ++j) {
            float ax = __shfl(xyg.x, j, 64);
            float ay = __shfl(xyg.y, j, 64);
            float ac = __shfl(cc,    j, 64);
            float sn = __shfl(ss,    j, 64);
            float bx = __shfl(scg.x, j, 64);
            float by = __shfl(scg.y, j, 64);
            int   g  = __shfl(gg,    j, 64);
            PROC_EXACT(ax, ay, ac, sn, bx, by, g)
        }
    }

    lt[w][0][lane] = v0; li[w][0][lane] = (unsigned short)i0;
    lt[w][1][lane] = v1; li[w][1][lane] = (unsigned short)i1;
    lt[w][2][lane] = v2; li[w][2][lane] = (unsigned short)i2;
    lt[w][3][lane] = v3; li[w][3][lane] = (unsigned short)i3;
    lt[w][4][lane] = v4; li[w][4][lane] = (unsigned short)i4;
    lt[w][5][lane] = v5; li[w][5][lane] = (unsigned short)i5;
    lt[w][6][lane] = v6; li[w][6][lane] = (unsigned short)i6;
    lt[w][7][lane] = v7; li[w][7][lane] = (unsigned short)i7;
    __syncthreads();   // the ONLY barrier

    // ---------------- Phase E: wave-0 final merge + blend ------------------
    if (w == 0) {
        v0 = INFINITY; v1 = INFINITY; v2 = INFINITY; v3 = INFINITY;
        v4 = INFINITY; v5 = INFINITY; v6 = INFINITY; v7 = INFINITY;
        i0 = 0; i1 = 0; i2 = 0; i3 = 0; i4 = 0; i5 = 0; i6 = 0; i7 = 0;
        // Ascending wave order == ascending segment == ascending gaussian
        // index -> identical selection/ordering to the single-stream ladder.
        for (int c = 0; c < NW; ++c) {
#pragma unroll
            for (int k = 0; k < 8; ++k) {
                float t2 = lt[c][k][lane];
                int   g  = (int)li[c][k][lane];
                LADDER(t2, g)
            }
        }
        float w0 = expf(-0.5f * v0), w1 = expf(-0.5f * v1);
        float w2 = expf(-0.5f * v2), w3 = expf(-0.5f * v3);
        float w4 = expf(-0.5f * v4), w5 = expf(-0.5f * v5);
        float w6 = expf(-0.5f * v6), w7 = expf(-0.5f * v7);
        float sum = w0 + w1 + w2 + w3 + w4 + w5 + w6 + w7;
        float inv = 1.0f / (sum + EPS);

        float oc0 = 0.f, oc1 = 0.f, oc2 = 0.f;
#define ACC(K)                                                  \
        {                                                       \
            float al = w##K * inv;                              \
            const float* f = feat + 3 * i##K;                   \
            oc0 = fmaf(al, f[0], oc0);                          \
            oc1 = fmaf(al, f[1], oc1);                          \
            oc2 = fmaf(al, f[2], oc2);                          \
        }
        ACC(0) ACC(1) ACC(2) ACC(3) ACC(4) ACC(5) ACC(6) ACC(7)
#undef ACC

        out[p]            = oc0;
        out[p + NPIX]     = oc1;
        out[p + 2 * NPIX] = oc2;
    }
}

extern "C" void kernel_launch(void* const* d_in, const int* in_sizes, int n_in,
                              void* d_out, int out_size, void* d_ws, size_t ws_size,
                              hipStream_t stream) {
    const float* xy    = (const float*)d_in[0];
    const float* scale = (const float*)d_in[1];
    const float* rot   = (const float*)d_in[2];
    const float* feat  = (const float*)d_in[3];
    float* out = (float*)d_out;

    fused_kernel<<<NTILES, 512, 0, stream>>>(xy, scale, rot, feat, out);
}

// Round 13
// 33.801 us; speedup vs baseline: 1.0504x; 1.0504x over previous
//
#include <hip/hip_runtime.h>
#include <math.h>

#define N_GAUSS 2048
#define IMG_H 256
#define IMG_W 256
#define NPIX (IMG_H * IMG_W)
#define EPS 1e-4f

#define TILE 8
#define TILES_X (IMG_W / TILE)             // 32
#define NTILES (TILES_X * (IMG_H / TILE))  // 1024
#define NW 8                               // waves per block
#define SEG (N_GAUSS / NW)                 // 256 gaussians per wave-segment
#define CAP 64                             // LDS-staged candidates per segment
// Half-diagonal of the 8x8 pixel-center extent: 3.5*sqrt(2)/256 = 0.01933495
#define D_HALF 0.019336f                   // strictly above the exact value

// Strict-< sorted-insert ladder; lowest index wins ties (top_k stable order).
#define LADDER(T, G)                                                     \
    if ((T) < v7) {                                                      \
        const bool c0 = (T) < v0, c1 = (T) < v1, c2 = (T) < v2;          \
        const bool c3 = (T) < v3, c4 = (T) < v4, c5 = (T) < v5;          \
        const bool c6 = (T) < v6;                                        \
        v7 = c6 ? v6 : (T);            i7 = c6 ? i6 : (G);               \
        v6 = c6 ? (c5 ? v5 : (T)) : v6; i6 = c6 ? (c5 ? i5 : (G)) : i6;  \
        v5 = c5 ? (c4 ? v4 : (T)) : v5; i5 = c5 ? (c4 ? i4 : (G)) : i5;  \
        v4 = c4 ? (c3 ? v3 : (T)) : v4; i4 = c4 ? (c3 ? i3 : (G)) : i4;  \
        v3 = c3 ? (c2 ? v2 : (T)) : v3; i3 = c3 ? (c2 ? i2 : (G)) : i3;  \
        v2 = c2 ? (c1 ? v1 : (T)) : v2; i2 = c2 ? (c1 ? i1 : (G)) : i2;  \
        v1 = c1 ? (c0 ? v0 : (T)) : v1; i1 = c1 ? (c0 ? i0 : (G)) : i1;  \
        v0 = c0 ? (T) : v0;            i0 = c0 ? (G) : i0;               \
    }

// Compare-exchange on constant-indexed array elems (registers after unroll).
#define CE(a, i, j)                                   \
    { float lo_ = fminf(a[i], a[j]);                  \
      float hi_ = fmaxf(a[i], a[j]);                  \
      a[i] = lo_; a[j] = hi_; }

// Sort first 4 elements ascending (5 comparators).
#define SORT4(a) CE(a,0,1) CE(a,2,3) CE(a,0,2) CE(a,1,3) CE(a,1,2)

// In-wave exact top-8 reduce (verbatim from passing R6-R12 kernels): each lane
// holds an ascending 8-list (INF-padded); afterwards every lane holds the
// wave's exact sorted top-8 (cur[7] is wave-uniform).
__device__ __forceinline__ void top8_butterfly(float (&cur)[8]) {
#pragma unroll
    for (int m = 1; m < 64; m <<= 1) {
        float oth[8];
#pragma unroll
        for (int k = 0; k < 8; ++k) oth[k] = __shfl_xor(cur[k], m, 64);
        float t_[8];
#pragma unroll
        for (int k = 0; k < 8; ++k) t_[k] = fminf(cur[k], oth[7 - k]);
        CE(t_,0,4) CE(t_,1,5) CE(t_,2,6) CE(t_,3,7)
        CE(t_,0,2) CE(t_,1,3) CE(t_,4,6) CE(t_,5,7)
        CE(t_,0,1) CE(t_,2,3) CE(t_,4,5) CE(t_,6,7)
#pragma unroll
        for (int k = 0; k < 8; ++k) cur[k] = t_[k];
    }
}

// Bit-exact reference arithmetic (one rounding per op, no fma).
#define PROC_EXACT(AX, AY, AC, AS, BX, BY, G)                            \
    {                                                                    \
        float dx = __fsub_rn(px, (AX));                                  \
        float dy = __fsub_rn(py, (AY));                                  \
        float lx = __fadd_rn(__fmul_rn(dx, (AC)), __fmul_rn(dy, (AS)));  \
        float ly = __fadd_rn(__fmul_rn(-dx, (AS)), __fmul_rn(dy, (AC))); \
        float aa = __fmul_rn(lx, (BX));                                  \
        float bb = __fmul_rn(ly, (BY));                                  \
        float t2 = __fadd_rn(__fmul_rn(aa, aa), __fmul_rn(bb, bb));      \
        LADDER(t2, (G))                                                  \
    }

// 8-wave wave-local pipeline, one barrier (R12 structure, spill-free build):
//  A) wave w screens its own 256-gaussian segment; B) wave-local exact
//  8th-smallest cut (superset proof as R11/R12: V8_p(global) <= V8_p(segment)
//  <= cut_w; Lipschitz rlo <= r_p; 0.01 slack absorbs fp32/trig error);
//  C) register-ballot ordered compaction + LDS staging; D) masked f64 sincos
//  batch (bit-identical trig) + LDS-broadcast exact ladder, ascending index;
//  E) barrier, wave 0 merges 8 ascending lists + blend.
__launch_bounds__(512)
__global__ void fused_kernel(const float* __restrict__ xy,
                             const float* __restrict__ scale,
                             const float* __restrict__ rot,
                             const float* __restrict__ feat,
                             float* __restrict__ out) {
    __shared__ float4 qa[NW][CAP];            // 8 KB: staged x,y,sx,sy
    __shared__ float2 qt[NW][CAP];            // 4 KB: rot -> (cos,sin)
    __shared__ unsigned short qidx[NW][SEG];  // 4 KB: candidate ids (full seg)
    __shared__ float          lt[NW][8][64];  // 16 KB merge values
    __shared__ unsigned short li[NW][8][64];  // 8 KB merge indices

    const int tid  = threadIdx.x;
    const int lane = tid & 63;
    const int w    = tid >> 6;
    const int tile = blockIdx.x;

    // ---------------- Phase A: wave-local fp32 screen ----------------------
    const float cx = (float)((tile & (TILES_X - 1)) * TILE + 4) * (1.0f / IMG_W);
    const float cy = (float)((tile / TILES_X) * TILE + 4) * (1.0f / IMG_H);

    float rot_r[4], rlo_r[4], cur[8];
#pragma unroll
    for (int s = 0; s < 4; ++s) {
        int g = w * SEG + s * 64 + lane;
        float2 xyg = ((const float2*)xy)[g];
        float2 scg = ((const float2*)scale)[g];
        rot_r[s] = rot[g];
        float sn, cs2;
        __sincosf(rot_r[s], &sn, &cs2);
        float dx = cx - xyg.x;
        float dy = cy - xyg.y;
        float lx = dx * cs2 + dy * sn;
        float ly = dy * cs2 - dx * sn;
        float a  = lx * scg.x;
        float b  = ly * scg.y;
        float rr = sqrtf(a * a + b * b);
        float m  = fmaxf(scg.x, scg.y) * D_HALF;
        rlo_r[s] = rr - m;
        cur[s]   = rr + m;
    }
    cur[4] = INFINITY; cur[5] = INFINITY; cur[6] = INFINITY; cur[7] = INFINITY;
    SORT4(cur)

    // ---------------- Phase B: wave-local exact cut (no barrier) -----------
    top8_butterfly(cur);
    float cut = cur[7];
    cut = cut + 0.01f + 1e-4f * cut;     // slack >> all error budgets

    // ---------------- Phase C: register-ballot ordered compaction ----------
    unsigned base = 0;
#pragma unroll
    for (int s = 0; s < 4; ++s) {
        int g = w * SEG + s * 64 + lane;
        bool keep = rlo_r[s] <= cut;
        unsigned long long mask = __ballot(keep);
        if (keep) {
            unsigned pos = base + (unsigned)__popcll(mask & ((1ull << lane) - 1ull));
            qidx[w][pos] = (unsigned short)g;
            if (pos < CAP) {
                float2 xyg = ((const float2*)xy)[g];   // L1/L2 hit
                float2 scg = ((const float2*)scale)[g];
                qa[w][pos] = make_float4(xyg.x, xyg.y, scg.x, scg.y);
                qt[w][pos].x = rot_r[s];
            }
        }
        base += (unsigned)__popcll(mask);
    }
    const int cnt = (int)base;           // wave-uniform (ballot-derived)

    // ---------------- Phase D: bit-exact top-8 over own segment ------------
    const int jcap = cnt < CAP ? cnt : CAP;
    if (lane < jcap) {
        // Correctly-rounded fp32 trig via f64 sincos — bit-identical to the
        // (float)cos((double)r) path used since R2.
        double sd, cd;
        sincos((double)qt[w][lane].x, &sd, &cd);
        qt[w][lane] = make_float2((float)cd, (float)sd);
    }

    const int pxi = (tile & (TILES_X - 1)) * TILE + (lane & 7);
    const int pyi = (tile / TILES_X) * TILE + (lane >> 3);
    const int p   = pyi * IMG_W + pxi;
    const float px = (pxi + 0.5f) * (1.0f / IMG_W);
    const float py = (pyi + 0.5f) * (1.0f / IMG_H);

    float v0 = INFINITY, v1 = INFINITY, v2 = INFINITY, v3 = INFINITY;
    float v4 = INFINITY, v5 = INFINITY, v6 = INFINITY, v7 = INFINITY;
    int   i0 = 0, i1 = 0, i2 = 0, i3 = 0, i4 = 0, i5 = 0, i6 = 0, i7 = 0;

    for (int j = 0; j < jcap; ++j) {
        float4 a4 = qa[w][j];            // uniform addr -> LDS broadcast
        float2 ct = qt[w][j];
        int    g  = (int)qidx[w][j];
        PROC_EXACT(a4.x, a4.y, ct.x, ct.y, a4.z, a4.w, g)
    }
    // Overflow (cnt > CAP): rare/never for this input; R7-style shuffle
    // broadcast batches, values bit-identical (global reload + f64 trig).
    for (int b = CAP; b < cnt; b += 64) {
        int t = b + lane;
        int gg = (t < cnt) ? (int)qidx[w][t] : 0;
        float2 xyg = ((const float2*)xy)[gg];
        float2 scg = ((const float2*)scale)[gg];
        double sd, cd;
        sincos((double)rot[gg], &sd, &cd);
        float cc = (float)cd, ss = (float)sd;
        int lim = cnt - b; if (lim > 64) lim = 64;
        for (int j = 0; j < lim; ++j) {
            float ax = __shfl(xyg.x, j, 64);
            float ay = __shfl(xyg.y, j, 64);
            float ac = __shfl(cc,    j, 64);
            float sn = __shfl(ss,    j, 64);
            float bx = __shfl(scg.x, j, 64);
            float by = __shfl(scg.y, j, 64);
            int   g  = __shfl(gg,    j, 64);
            PROC_EXACT(ax, ay, ac, sn, bx, by, g)
        }
    }

    lt[w][0][lane] = v0; li[w][0][lane] = (unsigned short)i0;
    lt[w][1][lane] = v1; li[w][1][lane] = (unsigned short)i1;
    lt[w][2][lane] = v2; li[w][2][lane] = (unsigned short)i2;
    lt[w][3][lane] = v3; li[w][3][lane] = (unsigned short)i3;
    lt[w][4][lane] = v4; li[w][4][lane] = (unsigned short)i4;
    lt[w][5][lane] = v5; li[w][5][lane] = (unsigned short)i5;
    lt[w][6][lane] = v6; li[w][6][lane] = (unsigned short)i6;
    lt[w][7][lane] = v7; li[w][7][lane] = (unsigned short)i7;
    __syncthreads();   // the ONLY barrier

    // ---------------- Phase E: wave-0 final merge + blend ------------------
    if (w == 0) {
        v0 = INFINITY; v1 = INFINITY; v2 = INFINITY; v3 = INFINITY;
        v4 = INFINITY; v5 = INFINITY; v6 = INFINITY; v7 = INFINITY;
        i0 = 0; i1 = 0; i2 = 0; i3 = 0; i4 = 0; i5 = 0; i6 = 0; i7 = 0;
        // Ascending wave order == ascending segment == ascending gaussian
        // index -> identical selection/ordering to the single-stream ladder.
        for (int c = 0; c < NW; ++c) {
#pragma unroll
            for (int k = 0; k < 8; ++k) {
                float t2 = lt[c][k][lane];
                int   g  = (int)li[c][k][lane];
                LADDER(t2, g)
            }
        }
        float w0 = expf(-0.5f * v0), w1 = expf(-0.5f * v1);
        float w2 = expf(-0.5f * v2), w3 = expf(-0.5f * v3);
        float w4 = expf(-0.5f * v4), w5 = expf(-0.5f * v5);
        float w6 = expf(-0.5f * v6), w7 = expf(-0.5f * v7);
        float sum = w0 + w1 + w2 + w3 + w4 + w5 + w6 + w7;
        float inv = 1.0f / (sum + EPS);

        float oc0 = 0.f, oc1 = 0.f, oc2 = 0.f;
#define ACC(K)                                                  \
        {                                                       \
            float al = w##K * inv;                              \
            const float* f = feat + 3 * i##K;                   \
            oc0 = fmaf(al, f[0], oc0);                          \
            oc1 = fmaf(al, f[1], oc1);                          \
            oc2 = fmaf(al, f[2], oc2);                          \
        }
        ACC(0) ACC(1) ACC(2) ACC(3) ACC(4) ACC(5) ACC(6) ACC(7)
#undef ACC

        out[p]            = oc0;
        out[p + NPIX]     = oc1;
        out[p + 2 * NPIX] = oc2;
    }
}

extern "C" void kernel_launch(void* const* d_in, const int* in_sizes, int n_in,
                              void* d_out, int out_size, void* d_ws, size_t ws_size,
                              hipStream_t stream) {
    const float* xy    = (const float*)d_in[0];
    const float* scale = (const float*)d_in[1];
    const float* rot   = (const float*)d_in[2];
    const float* feat  = (const float*)d_in[3];
    float* out = (float*)d_out;

    fused_kernel<<<NTILES, 512, 0, stream>>>(xy, scale, rot, feat, out);
}

// Round 14
// 24.682 us; speedup vs baseline: 1.4384x; 1.3695x over previous
//
#include <hip/hip_runtime.h>
#include <math.h>

#define N_GAUSS 2048
#define IMG_H 256
#define IMG_W 256
#define NPIX (IMG_H * IMG_W)
#define EPS 1e-4f

#define TILE 8
#define TILES_X (IMG_W / TILE)             // 32
#define NTILES (TILES_X * (IMG_H / TILE))  // 1024
#define SEG 512                            // gaussians per wave-segment
// Half-diagonal of the 8x8 pixel-center extent: 3.5*sqrt(2)/256 = 0.01933495
#define D_HALF 0.019336f                   // strictly above the exact value

// Strict-< sorted-insert ladder; lowest index wins ties (top_k stable order).
#define LADDER(T, G)                                                     \
    if ((T) < v7) {                                                      \
        const bool c0 = (T) < v0, c1 = (T) < v1, c2 = (T) < v2;          \
        const bool c3 = (T) < v3, c4 = (T) < v4, c5 = (T) < v5;          \
        const bool c6 = (T) < v6;                                        \
        v7 = c6 ? v6 : (T);            i7 = c6 ? i6 : (G);               \
        v6 = c6 ? (c5 ? v5 : (T)) : v6; i6 = c6 ? (c5 ? i5 : (G)) : i6;  \
        v5 = c5 ? (c4 ? v4 : (T)) : v5; i5 = c5 ? (c4 ? i4 : (G)) : i5;  \
        v4 = c4 ? (c3 ? v3 : (T)) : v4; i4 = c4 ? (c3 ? i3 : (G)) : i4;  \
        v3 = c3 ? (c2 ? v2 : (T)) : v3; i3 = c3 ? (c2 ? i2 : (G)) : i3;  \
        v2 = c2 ? (c1 ? v1 : (T)) : v2; i2 = c2 ? (c1 ? i1 : (G)) : i2;  \
        v1 = c1 ? (c0 ? v0 : (T)) : v1; i1 = c1 ? (c0 ? i0 : (G)) : i1;  \
        v0 = c0 ? (T) : v0;            i0 = c0 ? (G) : i0;               \
    }

// values-only ladder (screening)
#define VLADDER(T)                                                       \
    if ((T) < v7) {                                                      \
        const bool c0 = (T) < v0, c1 = (T) < v1, c2 = (T) < v2;          \
        const bool c3 = (T) < v3, c4 = (T) < v4, c5 = (T) < v5;          \
        const bool c6 = (T) < v6;                                        \
        v7 = c6 ? v6 : (T);                                              \
        v6 = c6 ? (c5 ? v5 : (T)) : v6;                                  \
        v5 = c5 ? (c4 ? v4 : (T)) : v5;                                  \
        v4 = c4 ? (c3 ? v3 : (T)) : v4;                                  \
        v3 = c3 ? (c2 ? v2 : (T)) : v3;                                  \
        v2 = c2 ? (c1 ? v1 : (T)) : v2;                                  \
        v1 = c1 ? (c0 ? v0 : (T)) : v1;                                  \
        v0 = c0 ? (T) : v0;                                              \
    }

// Compare-exchange on constant-indexed array elems (registers after unroll).
#define CE(a, i, j)                                   \
    { float lo_ = fminf(a[i], a[j]);                  \
      float hi_ = fmaxf(a[i], a[j]);                  \
      a[i] = lo_; a[j] = hi_; }

// A := sorted 8 smallest of (A ∪ B); A,B ascending. Selection-only (exact).
#define MERGE8(A, B)                                  \
    { float t_[8];                                    \
      t_[0] = fminf(A[0], B[7]); t_[1] = fminf(A[1], B[6]); \
      t_[2] = fminf(A[2], B[5]); t_[3] = fminf(A[3], B[4]); \
      t_[4] = fminf(A[4], B[3]); t_[5] = fminf(A[5], B[2]); \
      t_[6] = fminf(A[6], B[1]); t_[7] = fminf(A[7], B[0]); \
      CE(t_,0,4) CE(t_,1,5) CE(t_,2,6) CE(t_,3,7)     \
      CE(t_,0,2) CE(t_,1,3) CE(t_,4,6) CE(t_,5,7)     \
      CE(t_,0,1) CE(t_,2,3) CE(t_,4,5) CE(t_,6,7)     \
      A[0]=t_[0]; A[1]=t_[1]; A[2]=t_[2]; A[3]=t_[3]; \
      A[4]=t_[4]; A[5]=t_[5]; A[6]=t_[6]; A[7]=t_[7]; }

// Single fused kernel: fp32 conservative cull + exact (f64-trig) top-8 + blend.
// (Verbatim R7 kernel — the 24.8 us PASS; empirical best across R2-R13.)
__launch_bounds__(256)
__global__ void fused_kernel(const float* __restrict__ xy,
                             const float* __restrict__ scale,
                             const float* __restrict__ rot,
                             const float* __restrict__ feat,
                             float* __restrict__ out) {
    __shared__ float rlo[N_GAUSS];            // 8 KB: r(center)-m per gaussian
    __shared__ float wlist[4][8];             // per-wave sorted top-8 of rp
    __shared__ float s_cut;
    __shared__ unsigned short qidx[N_GAUSS];  // 4 KB: per-segment candidates
    __shared__ int qcnt[4];
    __shared__ float          lt[4][8][64];   // 8 KB merge buf
    __shared__ unsigned short li[4][8][64];   // 4 KB

    const int tid  = threadIdx.x;
    const int lane = tid & 63;
    const int w    = tid >> 6;
    const int tile = blockIdx.x;

    // ---------------- Phase A: fp32 screen of all gaussians vs tile center -
    const float cx = (float)((tile & (TILES_X - 1)) * TILE + 4) * (1.0f / IMG_W);
    const float cy = (float)((tile / TILES_X) * TILE + 4) * (1.0f / IMG_H);
    float cur[8];
    {
        float v0 = INFINITY, v1 = INFINITY, v2 = INFINITY, v3 = INFINITY;
        float v4 = INFINITY, v5 = INFINITY, v6 = INFINITY, v7 = INFINITY;
#pragma unroll
        for (int r = 0; r < N_GAUSS / 256; ++r) {
            int g = r * 256 + tid;
            float2 xyg = ((const float2*)xy)[g];
            float2 scg = ((const float2*)scale)[g];
            float  rg  = rot[g];
            float s, c;
            __sincosf(rg, &s, &c);
            float dx = cx - xyg.x;
            float dy = cy - xyg.y;
            float lx = dx * c + dy * s;
            float ly = dy * c - dx * s;
            float a  = lx * scg.x;
            float b  = ly * scg.y;
            float rr = sqrtf(a * a + b * b);
            float m  = fmaxf(scg.x, scg.y) * D_HALF;
            rlo[g]   = rr - m;
            float rp = rr + m;
            VLADDER(rp)
        }
        cur[0] = v0; cur[1] = v1; cur[2] = v2; cur[3] = v3;
        cur[4] = v4; cur[5] = v5; cur[6] = v6; cur[7] = v7;
    }

    // ---------------- Phase B: exact top-8 reduce (register bitonic) -------
#pragma unroll
    for (int m = 1; m < 64; m <<= 1) {
        float oth[8];
#pragma unroll
        for (int k = 0; k < 8; ++k) oth[k] = __shfl_xor(cur[k], m, 64);
        float t_[8];
#pragma unroll
        for (int k = 0; k < 8; ++k) t_[k] = fminf(cur[k], oth[7 - k]);
        CE(t_,0,4) CE(t_,1,5) CE(t_,2,6) CE(t_,3,7)
        CE(t_,0,2) CE(t_,1,3) CE(t_,4,6) CE(t_,5,7)
        CE(t_,0,1) CE(t_,2,3) CE(t_,4,5) CE(t_,6,7)
#pragma unroll
        for (int k = 0; k < 8; ++k) cur[k] = t_[k];
    }
    if (lane == 0) {
#pragma unroll
        for (int k = 0; k < 8; ++k) wlist[w][k] = cur[k];
    }
    __syncthreads();

    if (tid == 0) {
        float A[8], B[8], C2[8], D2[8];
#pragma unroll
        for (int k = 0; k < 8; ++k) {
            A[k]  = wlist[0][k];
            B[k]  = wlist[1][k];
            C2[k] = wlist[2][k];
            D2[k] = wlist[3][k];
        }
        MERGE8(A, B)
        MERGE8(C2, D2)
        MERGE8(A, C2)
        float cut = A[7];
        s_cut = cut + 0.01f + 1e-4f * cut;  // slack >> trig + float error budgets
    }
    __syncthreads();
    const float cut = s_cut;

    // ---------------- Phase C: wave-parallel ordered compaction ------------
    {
        const int segbase = w * SEG;
        unsigned base = 0;
        for (int s2 = 0; s2 < SEG / 64; ++s2) {
            int g = segbase + s2 * 64 + lane;
            bool keep = rlo[g] <= cut;
            unsigned long long mask = __ballot(keep);
            unsigned pos = (unsigned)__popcll(mask & ((1ull << lane) - 1ull));
            if (keep) qidx[segbase + base + pos] = (unsigned short)g;
            base += (unsigned)__popcll(mask);
        }
        if (lane == 0) qcnt[w] = (int)base;
    }
    __syncthreads();

    // ---------------- Phase D: bit-exact top-8 over own segment ------------
    const int pxi = (tile & (TILES_X - 1)) * TILE + (lane & 7);
    const int pyi = (tile / TILES_X) * TILE + (lane >> 3);
    const int p   = pyi * IMG_W + pxi;
    const float px = (pxi + 0.5f) * (1.0f / IMG_W);
    const float py = (pyi + 0.5f) * (1.0f / IMG_H);

    float v0 = INFINITY, v1 = INFINITY, v2 = INFINITY, v3 = INFINITY;
    float v4 = INFINITY, v5 = INFINITY, v6 = INFINITY, v7 = INFINITY;
    int   i0 = 0, i1 = 0, i2 = 0, i3 = 0, i4 = 0, i5 = 0, i6 = 0, i7 = 0;

    {
        const int segbase = w * SEG;
        const int cnt = qcnt[w];
        for (int b = 0; b < cnt; b += 64) {
            int t = b + lane;
            int gg = (t < cnt) ? (int)qidx[segbase + t] : 0;
            // Exact per-candidate params (one candidate per lane).
            float2 xyg = ((const float2*)xy)[gg];
            float2 scg = ((const float2*)scale)[gg];
            double rg  = (double)rot[gg];
            // Correctly-rounded fp32 trig via f64 (bit-identical to prep path).
            float cc = (float)cos(rg);
            float ss = (float)sin(rg);
            int lim = cnt - b; if (lim > 64) lim = 64;
            for (int j = 0; j < lim; ++j) {
                // Broadcast candidate j's params from lane j.
                float ax = __shfl(xyg.x, j, 64);
                float ay = __shfl(xyg.y, j, 64);
                float ac = __shfl(cc,    j, 64);
                float sn = __shfl(ss,    j, 64);
                float bx = __shfl(scg.x, j, 64);
                float by = __shfl(scg.y, j, 64);
                int   g  = __shfl(gg,    j, 64);
                // Bit-exact reference arithmetic (one rounding per op, no fma):
                float dx = __fsub_rn(px, ax);
                float dy = __fsub_rn(py, ay);
                float lx = __fadd_rn(__fmul_rn(dx, ac), __fmul_rn(dy, sn));
                float ly = __fadd_rn(__fmul_rn(-dx, sn), __fmul_rn(dy, ac));
                float aa = __fmul_rn(lx, bx);
                float bb = __fmul_rn(ly, by);
                float t2 = __fadd_rn(__fmul_rn(aa, aa), __fmul_rn(bb, bb));
                LADDER(t2, g)
            }
        }
    }

    lt[w][0][lane] = v0; li[w][0][lane] = (unsigned short)i0;
    lt[w][1][lane] = v1; li[w][1][lane] = (unsigned short)i1;
    lt[w][2][lane] = v2; li[w][2][lane] = (unsigned short)i2;
    lt[w][3][lane] = v3; li[w][3][lane] = (unsigned short)i3;
    lt[w][4][lane] = v4; li[w][4][lane] = (unsigned short)i4;
    lt[w][5][lane] = v5; li[w][5][lane] = (unsigned short)i5;
    lt[w][6][lane] = v6; li[w][6][lane] = (unsigned short)i6;
    lt[w][7][lane] = v7; li[w][7][lane] = (unsigned short)i7;
    __syncthreads();

    if (w == 0) {
        v0 = INFINITY; v1 = INFINITY; v2 = INFINITY; v3 = INFINITY;
        v4 = INFINITY; v5 = INFINITY; v6 = INFINITY; v7 = INFINITY;
        i0 = 0; i1 = 0; i2 = 0; i3 = 0; i4 = 0; i5 = 0; i6 = 0; i7 = 0;
        // Ascending wave order == ascending segment == ascending gaussian
        // index -> identical selection/ordering to the single-stream ladder.
        for (int c = 0; c < 4; ++c) {
#pragma unroll
            for (int k = 0; k < 8; ++k) {
                float t2 = lt[c][k][lane];
                int   g  = (int)li[c][k][lane];
                LADDER(t2, g)
            }
        }
        float w0 = expf(-0.5f * v0), w1 = expf(-0.5f * v1);
        float w2 = expf(-0.5f * v2), w3 = expf(-0.5f * v3);
        float w4 = expf(-0.5f * v4), w5 = expf(-0.5f * v5);
        float w6 = expf(-0.5f * v6), w7 = expf(-0.5f * v7);
        float sum = w0 + w1 + w2 + w3 + w4 + w5 + w6 + w7;
        float inv = 1.0f / (sum + EPS);

        float oc0 = 0.f, oc1 = 0.f, oc2 = 0.f;
#define ACC(K)                                                  \
        {                                                       \
            float al = w##K * inv;                              \
            const float* f = feat + 3 * i##K;                   \
            oc0 = fmaf(al, f[0], oc0);                          \
            oc1 = fmaf(al, f[1], oc1);                          \
            oc2 = fmaf(al, f[2], oc2);                          \
        }
        ACC(0) ACC(1) ACC(2) ACC(3) ACC(4) ACC(5) ACC(6) ACC(7)
#undef ACC

        out[p]            = oc0;
        out[p + NPIX]     = oc1;
        out[p + 2 * NPIX] = oc2;
    }
}

extern "C" void kernel_launch(void* const* d_in, const int* in_sizes, int n_in,
                              void* d_out, int out_size, void* d_ws, size_t ws_size,
                              hipStream_t stream) {
    const float* xy    = (const float*)d_in[0];
    const float* scale = (const float*)d_in[1];
    const float* rot   = (const float*)d_in[2];
    const float* feat  = (const float*)d_in[3];
    float* out = (float*)d_out;

    fused_kernel<<<NTILES, 256, 0, stream>>>(xy, scale, rot, feat, out);
}